// Round 12
// baseline (83.869 us; speedup 1.0000x reference)
//
#include <hip/hip_runtime.h>

// Problem constants (B,S,D,R) = (4,1024,1024,64)
#define SS 1024
#define DD 1024
#define RR 64
#define NB 4
#define NROWS (NB * SS)   // 4096

// ---- fused proj: 32 strips x 128 rows, KSPLIT=16 (64 k each) --------------
#define STRIPS 32
#define SROWS 128
#define KSPL 16
#define KB 64
#define ATS 132                        // AT row stride: 528B, 16B-aligned

#define T_F    ((size_t)NROWS * RR)            // 256K floats = 1 MB
#define PART_F ((size_t)KSPL * T_F)            // 16 MB
#define WS_NEED ((PART_F + T_F + 64) * 4)

// ---------------------------------------------------------------------------
// proj_fused: grid 512 = slice*STRIPS + strip  (=> blockIdx % 8 == strip % 8:
// all 16 slices of a strip land on ONE XCD -> partials stay XCD-local).
// Each block: 128 rows x 64 cols x 64 k -> partial slice (plain stores).
// Arrival counter per strip; the 16th block reduces the strip's 16 slices
// (reads are local-XCD dirty L2 lines) and writes t.
// ---------------------------------------------------------------------------
__global__ __launch_bounds__(128) void proj_fused_kernel(const float* __restrict__ batch,
                                                         const float* __restrict__ proj,
                                                         float* __restrict__ part,
                                                         float* __restrict__ t,
                                                         unsigned int* __restrict__ ctr) {
    __shared__ __align__(16) float AT[KB][ATS];   // [k][row] 33.8 KB
    __shared__ __align__(16) float Pt[KB][RR];    // [k][r]   16 KB
    __shared__ int last_flag;

    const int tid   = threadIdx.x;                // 0..127
    const int strip = blockIdx.x % STRIPS;
    const int slice = blockIdx.x / STRIPS;        // 0..15
    const int row0  = strip * SROWS;
    const int kbase = slice * KB;

    // ---- stage batch transposed (128 rows x 64 k) + proj chunk ----
    {
        const int rbase = tid >> 4;               // 0..7
        const int k4    = tid & 15;               // float4 index along k
        float4 v[16];
#pragma unroll
        for (int p = 0; p < 16; ++p) {
            const int row = rbase + p * 8;
            v[p] = *reinterpret_cast<const float4*>(
                &batch[(size_t)(row0 + row) * DD + kbase + k4 * 4]);
        }
#pragma unroll
        for (int p = 0; p < 16; ++p) {
            const int row = rbase + p * 8;
            AT[k4 * 4 + 0][row] = v[p].x;
            AT[k4 * 4 + 1][row] = v[p].y;
            AT[k4 * 4 + 2][row] = v[p].z;
            AT[k4 * 4 + 3][row] = v[p].w;
        }
        const float4* psrc = reinterpret_cast<const float4*>(proj + (size_t)kbase * RR);
#pragma unroll
        for (int i = 0; i < 8; ++i)
            reinterpret_cast<float4*>(Pt)[i * 128 + tid] = psrc[i * 128 + tid];
    }
    __syncthreads();

    // ---- compute: 8 rows x 8 cols per thread (16 row-groups x 8 col-groups)
    const int tx = tid & 7;
    const int ty = tid >> 3;                      // 0..15

    float acc[8][8];
#pragma unroll
    for (int i = 0; i < 8; ++i)
#pragma unroll
        for (int j = 0; j < 8; ++j) acc[i][j] = 0.0f;

#pragma unroll 4
    for (int k = 0; k < KB; ++k) {
        const float4 a0 = *reinterpret_cast<const float4*>(&AT[k][ty * 8 + 0]);
        const float4 a1 = *reinterpret_cast<const float4*>(&AT[k][ty * 8 + 4]);
        const float4 p0 = *reinterpret_cast<const float4*>(&Pt[k][tx * 8 + 0]);
        const float4 p1 = *reinterpret_cast<const float4*>(&Pt[k][tx * 8 + 4]);
        const float a[8] = {a0.x, a0.y, a0.z, a0.w, a1.x, a1.y, a1.z, a1.w};
        const float p[8] = {p0.x, p0.y, p0.z, p0.w, p1.x, p1.y, p1.z, p1.w};
#pragma unroll
        for (int i = 0; i < 8; ++i)
#pragma unroll
            for (int j = 0; j < 8; ++j)
                acc[i][j] = fmaf(a[i], p[j], acc[i][j]);
    }

    // ---- store partial slice (plain stores, no init needed) ----
    float* slice_p = part + (size_t)slice * T_F;
#pragma unroll
    for (int i = 0; i < 8; ++i) {
        const size_t base = (size_t)(row0 + ty * 8 + i) * RR + tx * 8;
        float4 o0 = {acc[i][0], acc[i][1], acc[i][2], acc[i][3]};
        float4 o1 = {acc[i][4], acc[i][5], acc[i][6], acc[i][7]};
        *reinterpret_cast<float4*>(&slice_p[base + 0]) = o0;
        *reinterpret_cast<float4*>(&slice_p[base + 4]) = o1;
    }

    // ---- arrival counter: last block of this strip reduces ----
    __syncthreads();
    __threadfence();                               // release partials
    if (tid == 0) {
        const unsigned int old = atomicAdd(&ctr[strip], 1u);
        last_flag = (old == KSPL - 1);
    }
    __syncthreads();
    if (!last_flag) return;
    __threadfence();                               // acquire others' partials

    // winner: sum 16 slices for this strip's 128 rows -> t
    const float4* p4 = reinterpret_cast<const float4*>(part);
    const int base4 = strip * (SROWS * RR / 4);    // strip's first float4 in t
#pragma unroll
    for (int j = 0; j < 16; ++j) {
        const int o = j * 128 + tid;               // 0..2047
        float4 s = p4[base4 + o];
#pragma unroll
        for (int sl = 1; sl < KSPL; ++sl) {
            const float4 v = p4[(size_t)sl * (T_F / 4) + base4 + o];
            s.x += v.x; s.y += v.y; s.z += v.z; s.w += v.w;
        }
        reinterpret_cast<float4*>(t)[base4 + o] = s;
    }
}

// Zero the 32 strip counters (tiny).
__global__ void zero_ctr_kernel(unsigned int* __restrict__ ctr) {
    if (threadIdx.x < STRIPS) ctr[threadIdx.x] = 0u;
}

// ---------------------------------------------------------------------------
// dist (identical to rounds 6-11, ~7us): out = n_i + n_j - 2 * t_i . t_j
// ---------------------------------------------------------------------------
#define TPAD 68

__global__ __launch_bounds__(256) void dist_kernel(const float* __restrict__ t,
                                                   float* __restrict__ out) {
    __shared__ __align__(16) float tiT[RR][TPAD];
    __shared__ __align__(16) float tjT[RR][TPAD];
    __shared__ float ni[64];
    __shared__ float nj[64];

    const int b  = blockIdx.z;
    const int i0 = blockIdx.y * 64;
    const int j0 = blockIdx.x * 64;
    const int tid = threadIdx.x;

    for (int idx = tid; idx < 2048; idx += 256) {
        const int tile = idx >> 10;
        const int e    = idx & 1023;
        const int row  = e >> 4;
        const int rseg = e & 15;
        const int src_row = b * SS + (tile ? j0 : i0) + row;
        const float4 v =
            *reinterpret_cast<const float4*>(&t[(size_t)src_row * RR + rseg * 4]);
        float (*dst)[TPAD] = tile ? tjT : tiT;
        dst[rseg * 4 + 0][row] = v.x;
        dst[rseg * 4 + 1][row] = v.y;
        dst[rseg * 4 + 2][row] = v.z;
        dst[rseg * 4 + 3][row] = v.w;
    }
    __syncthreads();

    if (tid < 128) {
        const int row = tid & 63;
        float (*src)[TPAD] = (tid >> 6) ? tjT : tiT;
        float s = 0.0f;
#pragma unroll
        for (int r = 0; r < RR; ++r) {
            const float v = src[r][row];
            s = fmaf(v, v, s);
        }
        if (tid >> 6) nj[row] = s; else ni[row] = s;
    }
    __syncthreads();

    const int tx = tid & 15;
    const int ty = tid >> 4;

    float acc[4][4];
#pragma unroll
    for (int i = 0; i < 4; ++i)
#pragma unroll
        for (int j = 0; j < 4; ++j) acc[i][j] = 0.0f;

#pragma unroll 4
    for (int r = 0; r < RR; ++r) {
        const float4 av = *reinterpret_cast<const float4*>(&tiT[r][ty * 4]);
        const float4 bv = *reinterpret_cast<const float4*>(&tjT[r][tx * 4]);
        const float a[4] = {av.x, av.y, av.z, av.w};
        const float c[4] = {bv.x, bv.y, bv.z, bv.w};
#pragma unroll
        for (int i = 0; i < 4; ++i)
#pragma unroll
            for (int j = 0; j < 4; ++j)
                acc[i][j] = fmaf(a[i], c[j], acc[i][j]);
    }

    const float nrow[4] = {ni[ty*4+0], ni[ty*4+1], ni[ty*4+2], ni[ty*4+3]};
    const float ncol[4] = {nj[tx*4+0], nj[tx*4+1], nj[tx*4+2], nj[tx*4+3]};
#pragma unroll
    for (int i = 0; i < 4; ++i) {
        float4 o;
        o.x = fmaf(-2.0f, acc[i][0], nrow[i] + ncol[0]);
        o.y = fmaf(-2.0f, acc[i][1], nrow[i] + ncol[1]);
        o.z = fmaf(-2.0f, acc[i][2], nrow[i] + ncol[2]);
        o.w = fmaf(-2.0f, acc[i][3], nrow[i] + ncol[3]);
        *reinterpret_cast<float4*>(
            &out[((size_t)(b * SS + i0 + ty * 4 + i)) * SS + j0 + tx * 4]) = o;
    }
}

// ---- fallback bits (tiny ws): own zero + atomic-combine proj --------------
__global__ __launch_bounds__(256) void zero_kernel(float* __restrict__ t) {
    const int idx = blockIdx.x * 256 + threadIdx.x;
    reinterpret_cast<float4*>(t)[idx] = {0.0f, 0.0f, 0.0f, 0.0f};
}

__global__ __launch_bounds__(256) void proj_atomic_kernel(const float* __restrict__ batch,
                                                          const float* __restrict__ proj,
                                                          float* __restrict__ t) {
    __shared__ __align__(16) float AT[64][68];
    __shared__ __align__(16) float Pt[64][RR];
    const int tid = threadIdx.x;
    const int row0 = blockIdx.x * 64;
    const int kbase = blockIdx.y * 128;
    const int tx = tid & 15, ty = tid >> 4;
    float acc[4][4] = {{0.0f}};
    for (int kt = 0; kt < 2; ++kt) {
        const int k0 = kbase + kt * 64;
        __syncthreads();
#pragma unroll
        for (int i = 0; i < 4; ++i) {
            const float4 a = *reinterpret_cast<const float4*>(
                &batch[(size_t)(row0 + i * 16 + ty) * DD + k0 + tx * 4]);
            AT[tx*4+0][i*16+ty] = a.x; AT[tx*4+1][i*16+ty] = a.y;
            AT[tx*4+2][i*16+ty] = a.z; AT[tx*4+3][i*16+ty] = a.w;
            reinterpret_cast<float4*>(Pt)[i * 256 + tid] =
                reinterpret_cast<const float4*>(proj + (size_t)k0 * RR)[i * 256 + tid];
        }
        __syncthreads();
#pragma unroll 8
        for (int k = 0; k < 64; ++k) {
            const float4 av = *reinterpret_cast<const float4*>(&AT[k][ty * 4]);
            const float4 pv = *reinterpret_cast<const float4*>(&Pt[k][tx * 4]);
            const float a[4] = {av.x, av.y, av.z, av.w};
            const float p[4] = {pv.x, pv.y, pv.z, pv.w};
#pragma unroll
            for (int i = 0; i < 4; ++i)
#pragma unroll
                for (int j = 0; j < 4; ++j)
                    acc[i][j] = fmaf(a[i], p[j], acc[i][j]);
        }
    }
#pragma unroll
    for (int i = 0; i < 4; ++i)
#pragma unroll
        for (int j = 0; j < 4; ++j)
            atomicAdd(&t[(size_t)(row0 + ty*4 + i) * RR + tx*4 + j], acc[i][j]);
}

// ---------------------------------------------------------------------------
extern "C" void kernel_launch(void* const* d_in, const int* in_sizes, int n_in,
                              void* d_out, int out_size, void* d_ws, size_t ws_size,
                              hipStream_t stream) {
    const float* batch = (const float*)d_in[0];  // (4,1024,1024) f32
    const float* proj  = (const float*)d_in[1];  // (1024,64) f32
    float* out = (float*)d_out;                  // (4,1024,1024) f32
    float* ws  = (float*)d_ws;

    dim3 gB(SS / 64, SS / 64, NB);

    if (ws_size >= WS_NEED) {
        float* part = ws;                            // 16 MB
        float* t    = ws + PART_F;                   // 1 MB
        unsigned int* ctr = (unsigned int*)(t + T_F);

        zero_ctr_kernel<<<1, 64, 0, stream>>>(ctr);
        proj_fused_kernel<<<STRIPS * KSPL, 128, 0, stream>>>(batch, proj, part, t, ctr);
        dist_kernel<<<gB, 256, 0, stream>>>(t, out);
    } else {
        float* t = ws;
        zero_kernel<<<T_F / (256 * 4), 256, 0, stream>>>(t);
        dim3 gA(NROWS / 64, 8, 1);
        proj_atomic_kernel<<<gA, 256, 0, stream>>>(batch, proj, t);
        dist_kernel<<<gB, 256, 0, stream>>>(t, out);
    }
}

// Round 14
// 45.864 us; speedup vs baseline: 1.8287x; 1.8287x over previous
//
#include <hip/hip_runtime.h>

// Problem constants (B,S,D,R) = (4,1024,1024,64)
#define SS 1024
#define DD 1024
#define RR 64
#define NB 4
#define NROWS (NB * SS)   // 4096

#define T_F ((size_t)NROWS * RR)   // 256K floats = 1 MB

// ---- proj_full: 256 blocks x 16 rows, FULL K per block (no combine!) ------
#define PR 16          // rows per block
#define PBK 64         // k-tile
#define PNT (DD / PBK) // 16 tiles

// ---------------------------------------------------------------------------
// proj_full: t[row][r] = sum_k batch[row][k] * proj[k][r]
// One block owns 16 rows and the ENTIRE K reduction -> no partials, no
// atomics, no fences, no cross-XCD combine (R1-R12 evidence: every combine
// mechanism costs 25-45us in coherence traffic).
// Double-buffered LDS, global_load_lds staging (both tiles lane-linear),
// one barrier per K-tile. Inner loop: b32 broadcast + b128 + 4 FMA per k.
// ---------------------------------------------------------------------------
__global__ __launch_bounds__(256) void proj_full_kernel(const float* __restrict__ batch,
                                                        const float* __restrict__ proj,
                                                        float* __restrict__ t) {
    __shared__ __align__(16) float Ab[2][PR][PBK];   // [buf][row][k]  8 KB
    __shared__ __align__(16) float Pt[2][PBK][RR];   // [buf][k][r]   32 KB

    const int tid  = threadIdx.x;
    const int row0 = blockIdx.x * PR;
    const int wv   = __builtin_amdgcn_readfirstlane(tid >> 6);  // wave id 0..3
    const int ln   = tid & 63;

    // Per-wave staging geometry (global src per-lane, LDS dest wave-uniform):
    // batch tile: wave w -> rows 4w..4w+3, lane covers (row=ln>>4, k4=ln&15),
    //   LDS dest = &Ab[buf][4w][0] + lane*16B  (lane-linear ✓)
    // proj tile: 1024 float4; inst i of wave w covers f4 idx i*256+w*64+ln,
    //   LDS dest = Pt base + (i*256+w*64)*16B + lane*16B  (lane-linear ✓)
    const int srow = (ln >> 4);          // 0..3 within wave group
    const int sk4  = (ln & 15);          // float4 along k

    auto stage = [&](int kt, int buf) {
        const int k0 = kt * PBK;
        // batch: 16 rows x 64 k = 4KB, one 16B op per thread
        {
            const float* g = &batch[(size_t)(row0 + wv * 4 + srow) * DD + k0 + sk4 * 4];
            float* l = &Ab[buf][wv * 4][0];
            __builtin_amdgcn_global_load_lds((const __attribute__((address_space(1))) void*)g,
                                             (__attribute__((address_space(3))) void*)l,
                                             16, 0, 0);
        }
        // proj: 64 k x 64 r = 16KB, four 16B ops per thread
        const float* psrc = proj + (size_t)k0 * RR;
#pragma unroll
        for (int i = 0; i < 4; ++i) {
            const float* g = psrc + (size_t)(i * 256 + wv * 64 + ln) * 4;
            float* l = &Pt[buf][0][0] + (size_t)(i * 256 + wv * 64) * 4;
            __builtin_amdgcn_global_load_lds((const __attribute__((address_space(1))) void*)g,
                                             (__attribute__((address_space(3))) void*)l,
                                             16, 0, 0);
        }
    };

    // compute mapping: row = tid>>4 (0..15), tx = tid&15 -> cols tx*4..+3
    const int crow = tid >> 4;
    const int tx   = tid & 15;

    float4 acc = {0.0f, 0.0f, 0.0f, 0.0f};

    stage(0, 0);
    __syncthreads();                       // drain vmcnt -> buf0 ready

    for (int kt = 0; kt < PNT; ++kt) {
        const int buf = kt & 1;
        if (kt + 1 < PNT) stage(kt + 1, buf ^ 1);   // async, drains at barrier
#pragma unroll 8
        for (int k = 0; k < PBK; ++k) {
            const float a = Ab[buf][crow][k];
            const float4 p = *reinterpret_cast<const float4*>(&Pt[buf][k][tx * 4]);
            acc.x = fmaf(a, p.x, acc.x);
            acc.y = fmaf(a, p.y, acc.y);
            acc.z = fmaf(a, p.z, acc.z);
            acc.w = fmaf(a, p.w, acc.w);
        }
        __syncthreads();                   // barrier drains stage of kt+1
    }

    *reinterpret_cast<float4*>(&t[(size_t)(row0 + crow) * RR + tx * 4]) = acc;
}

// ---------------------------------------------------------------------------
// dist (identical to rounds 6-12, measured ~7-8us)
// ---------------------------------------------------------------------------
#define TPAD 68

__global__ __launch_bounds__(256) void dist_kernel(const float* __restrict__ t,
                                                   float* __restrict__ out) {
    __shared__ __align__(16) float tiT[RR][TPAD];
    __shared__ __align__(16) float tjT[RR][TPAD];
    __shared__ float ni[64];
    __shared__ float nj[64];

    const int b  = blockIdx.z;
    const int i0 = blockIdx.y * 64;
    const int j0 = blockIdx.x * 64;
    const int tid = threadIdx.x;

    for (int idx = tid; idx < 2048; idx += 256) {
        const int tile = idx >> 10;
        const int e    = idx & 1023;
        const int row  = e >> 4;
        const int rseg = e & 15;
        const int src_row = b * SS + (tile ? j0 : i0) + row;
        const float4 v =
            *reinterpret_cast<const float4*>(&t[(size_t)src_row * RR + rseg * 4]);
        float (*dst)[TPAD] = tile ? tjT : tiT;
        dst[rseg * 4 + 0][row] = v.x;
        dst[rseg * 4 + 1][row] = v.y;
        dst[rseg * 4 + 2][row] = v.z;
        dst[rseg * 4 + 3][row] = v.w;
    }
    __syncthreads();

    if (tid < 128) {
        const int row = tid & 63;
        float (*src)[TPAD] = (tid >> 6) ? tjT : tiT;
        float s = 0.0f;
#pragma unroll
        for (int r = 0; r < RR; ++r) {
            const float v = src[r][row];
            s = fmaf(v, v, s);
        }
        if (tid >> 6) nj[row] = s; else ni[row] = s;
    }
    __syncthreads();

    const int tx = tid & 15;
    const int ty = tid >> 4;

    float acc[4][4];
#pragma unroll
    for (int i = 0; i < 4; ++i)
#pragma unroll
        for (int j = 0; j < 4; ++j) acc[i][j] = 0.0f;

#pragma unroll 4
    for (int r = 0; r < RR; ++r) {
        const float4 av = *reinterpret_cast<const float4*>(&tiT[r][ty * 4]);
        const float4 bv = *reinterpret_cast<const float4*>(&tjT[r][tx * 4]);
        const float a[4] = {av.x, av.y, av.z, av.w};
        const float c[4] = {bv.x, bv.y, bv.z, bv.w};
#pragma unroll
        for (int i = 0; i < 4; ++i)
#pragma unroll
            for (int j = 0; j < 4; ++j)
                acc[i][j] = fmaf(a[i], c[j], acc[i][j]);
    }

    const float nrow[4] = {ni[ty*4+0], ni[ty*4+1], ni[ty*4+2], ni[ty*4+3]};
    const float ncol[4] = {nj[tx*4+0], nj[tx*4+1], nj[tx*4+2], nj[tx*4+3]};
#pragma unroll
    for (int i = 0; i < 4; ++i) {
        float4 o;
        o.x = fmaf(-2.0f, acc[i][0], nrow[i] + ncol[0]);
        o.y = fmaf(-2.0f, acc[i][1], nrow[i] + ncol[1]);
        o.z = fmaf(-2.0f, acc[i][2], nrow[i] + ncol[2]);
        o.w = fmaf(-2.0f, acc[i][3], nrow[i] + ncol[3]);
        *reinterpret_cast<float4*>(
            &out[((size_t)(b * SS + i0 + ty * 4 + i)) * SS + j0 + tx * 4]) = o;
    }
}

// ---- fallback (tiny ws): own zero + atomic-combine proj -------------------
__global__ __launch_bounds__(256) void zero_kernel(float* __restrict__ t) {
    const int idx = blockIdx.x * 256 + threadIdx.x;
    reinterpret_cast<float4*>(t)[idx] = {0.0f, 0.0f, 0.0f, 0.0f};
}

__global__ __launch_bounds__(256) void proj_atomic_kernel(const float* __restrict__ batch,
                                                          const float* __restrict__ proj,
                                                          float* __restrict__ t) {
    __shared__ __align__(16) float AT[64][68];
    __shared__ __align__(16) float Pt[64][RR];
    const int tid = threadIdx.x;
    const int row0 = blockIdx.x * 64;
    const int kbase = blockIdx.y * 128;
    const int tx = tid & 15, ty = tid >> 4;
    float acc[4][4] = {{0.0f}};
    for (int kt = 0; kt < 2; ++kt) {
        const int k0 = kbase + kt * 64;
        __syncthreads();
#pragma unroll
        for (int i = 0; i < 4; ++i) {
            const float4 a = *reinterpret_cast<const float4*>(
                &batch[(size_t)(row0 + i * 16 + ty) * DD + k0 + tx * 4]);
            AT[tx*4+0][i*16+ty] = a.x; AT[tx*4+1][i*16+ty] = a.y;
            AT[tx*4+2][i*16+ty] = a.z; AT[tx*4+3][i*16+ty] = a.w;
            reinterpret_cast<float4*>(Pt)[i * 256 + tid] =
                reinterpret_cast<const float4*>(proj + (size_t)k0 * RR)[i * 256 + tid];
        }
        __syncthreads();
#pragma unroll 8
        for (int k = 0; k < 64; ++k) {
            const float4 av = *reinterpret_cast<const float4*>(&AT[k][ty * 4]);
            const float4 pv = *reinterpret_cast<const float4*>(&Pt[k][tx * 4]);
            const float a[4] = {av.x, av.y, av.z, av.w};
            const float p[4] = {pv.x, pv.y, pv.z, pv.w};
#pragma unroll
            for (int i = 0; i < 4; ++i)
#pragma unroll
                for (int j = 0; j < 4; ++j)
                    acc[i][j] = fmaf(a[i], p[j], acc[i][j]);
        }
    }
#pragma unroll
    for (int i = 0; i < 4; ++i)
#pragma unroll
        for (int j = 0; j < 4; ++j)
            atomicAdd(&t[(size_t)(row0 + ty*4 + i) * RR + tx*4 + j], acc[i][j]);
}

// ---------------------------------------------------------------------------
extern "C" void kernel_launch(void* const* d_in, const int* in_sizes, int n_in,
                              void* d_out, int out_size, void* d_ws, size_t ws_size,
                              hipStream_t stream) {
    const float* batch = (const float*)d_in[0];  // (4,1024,1024) f32
    const float* proj  = (const float*)d_in[1];  // (1024,64) f32
    float* out = (float*)d_out;                  // (4,1024,1024) f32
    float* ws  = (float*)d_ws;

    dim3 gB(SS / 64, SS / 64, NB);

    if (ws_size >= T_F * 4) {
        float* t = ws;                           // 1 MB
        proj_full_kernel<<<NROWS / PR, 256, 0, stream>>>(batch, proj, t);
        dist_kernel<<<gB, 256, 0, stream>>>(t, out);
    } else {
        float* t = ws;
        zero_kernel<<<T_F / (256 * 4), 256, 0, stream>>>(t);
        dim3 gA(NROWS / 64, 8, 1);
        proj_atomic_kernel<<<gA, 256, 0, stream>>>(batch, proj, t);
        dist_kernel<<<gB, 256, 0, stream>>>(t, out);
    }
}